// Round 1
// baseline (878.339 us; speedup 1.0000x reference)
//
#include <hip/hip_runtime.h>
#include <math.h>

// Packed Viterbi (smoothed-max / CRF log-partition) forward.
// theta: [T, B, S, S] fp32, V_t[b,i] = logsumexp_j(theta[t,b,i,j] + V_{t-1}[b,j])
// out:   [B] fp32, out[b] = logsumexp_i(V_T[b,i])
constexpr int T = 256;
constexpr int B = 32;
constexpr int S = 128;

// One workgroup per batch. 1024 threads = 128 rows x 8 threads/row.
// Each thread handles 16 j-values as 4 interleaved float4 chunks
// (j = sub*4 + k*32) so each wave load instruction is a contiguous 1KB.
__global__ __launch_bounds__(1024)
void pv_forward_kernel(const float* __restrict__ theta, float* __restrict__ out) {
    const int b   = blockIdx.x;
    const int tid = threadIdx.x;
    const int row = tid >> 3;   // 0..127  (output state i)
    const int sub = tid & 7;    // 0..7    (j-partition within row)

    __shared__ float V[2][S];
    if (tid < S) V[0][tid] = 0.0f;   // V0 = 0
    __syncthreads();

    const float*  p       = theta + (size_t)b * S * S + (size_t)row * S + sub * 4;
    const size_t  tstride = (size_t)B * S * S;

    float4 thc[4], thn[4];
    #pragma unroll
    for (int k = 0; k < 4; ++k)
        thc[k] = *(const float4*)(p + k * 32);

    int cur = 0;
    for (int t = 0; t < T; ++t) {
        // Prefetch next timestep's theta while we do this step's math.
        if (t + 1 < T) {
            const float* pn = p + (size_t)(t + 1) * tstride;
            #pragma unroll
            for (int k = 0; k < 4; ++k)
                thn[k] = *(const float4*)(pn + k * 32);
        }

        // x[j] = theta[t,b,row,j] + V[j]
        float x[16];
        #pragma unroll
        for (int k = 0; k < 4; ++k) {
            const float4 v = *(const float4*)&V[cur][sub * 4 + k * 32];
            x[4 * k + 0] = thc[k].x + v.x;
            x[4 * k + 1] = thc[k].y + v.y;
            x[4 * k + 2] = thc[k].z + v.z;
            x[4 * k + 3] = thc[k].w + v.w;
        }

        // logsumexp over the 128 j's: local max/sum + 8-lane group reduce.
        float m = -3.402823466e38f;
        #pragma unroll
        for (int e = 0; e < 16; ++e) m = fmaxf(m, x[e]);
        m = fmaxf(m, __shfl_xor(m, 1));
        m = fmaxf(m, __shfl_xor(m, 2));
        m = fmaxf(m, __shfl_xor(m, 4));

        float s = 0.0f;
        #pragma unroll
        for (int e = 0; e < 16; ++e) s += __expf(x[e] - m);
        s += __shfl_xor(s, 1);
        s += __shfl_xor(s, 2);
        s += __shfl_xor(s, 4);

        if (sub == 0) V[cur ^ 1][row] = m + __logf(s);
        __syncthreads();
        cur ^= 1;

        #pragma unroll
        for (int k = 0; k < 4; ++k) thc[k] = thn[k];
    }

    // Terminal: out[b] = logsumexp_i(V[i]) over 128 states, done by wave 0.
    if (tid < 64) {
        float m1 = V[cur][tid];
        float m2 = V[cur][tid + 64];
        float mm = fmaxf(m1, m2);
        float ss = __expf(m1 - mm) + __expf(m2 - mm);
        #pragma unroll
        for (int off = 32; off > 0; off >>= 1) {
            float mo = __shfl_xor(mm, off);
            float so = __shfl_xor(ss, off);
            float mn = fmaxf(mm, mo);
            ss = ss * __expf(mm - mn) + so * __expf(mo - mn);
            mm = mn;
        }
        if (tid == 0) out[b] = mm + __logf(ss);
    }
}

extern "C" void kernel_launch(void* const* d_in, const int* in_sizes, int n_in,
                              void* d_out, int out_size, void* d_ws, size_t ws_size,
                              hipStream_t stream) {
    const float* theta = (const float*)d_in[0];
    float*       out   = (float*)d_out;
    pv_forward_kernel<<<B, 1024, 0, stream>>>(theta, out);
}